// Round 1
// baseline (235.696 us; speedup 1.0000x reference)
//
#include <hip/hip_runtime.h>

#define EPSC 1e-10f
#define BDIM 512
#define PDIM 1024
#define NDIM 1024
#define TDIM 32

#define BM 64
#define BN 64
#define BK 16

// ---------------- GEMM1: a = relu(x @ w_enc + b_enc); U = (a_sig - c0)/width (transposed [N][B]) ----
__global__ __launch_bounds__(256) void gemm1_kernel(
    const float* __restrict__ X, const float* __restrict__ W,
    const float* __restrict__ bias, const float* __restrict__ centers,
    float* __restrict__ Aout, float* __restrict__ U)
{
  const int K = PDIM, N = NDIM;
  __shared__ float As[BK][BM + 4];
  __shared__ float Bs[BK][BN + 4];
  int tid = threadIdx.x;
  int bm = blockIdx.y * BM;
  int bn = blockIdx.x * BN;
  int ty = tid >> 4, tx = tid & 15;
  float acc[4][4] = {};
  for (int k0 = 0; k0 < K; k0 += BK) {
    int r = tid >> 2;
    int c = (tid & 3) << 2;
    float4 av = *(const float4*)(X + (size_t)(bm + r) * K + k0 + c);
    As[c + 0][r] = av.x; As[c + 1][r] = av.y; As[c + 2][r] = av.z; As[c + 3][r] = av.w;
    int rb = tid >> 4;
    int cb = (tid & 15) << 2;
    *(float4*)(&Bs[rb][cb]) = *(const float4*)(W + (size_t)(k0 + rb) * N + bn + cb);
    __syncthreads();
#pragma unroll
    for (int k = 0; k < BK; ++k) {
      float4 a4 = *(const float4*)(&As[k][ty << 2]);
      float4 b4 = *(const float4*)(&Bs[k][tx << 2]);
      float ar[4] = {a4.x, a4.y, a4.z, a4.w};
      float br[4] = {b4.x, b4.y, b4.z, b4.w};
#pragma unroll
      for (int i = 0; i < 4; i++)
#pragma unroll
        for (int j = 0; j < 4; j++)
          acc[i][j] = fmaf(ar[i], br[j], acc[i][j]);
    }
    __syncthreads();
  }
  float c0 = centers[0];
  float invw = 1.0f / (centers[1] - centers[0]);
#pragma unroll
  for (int i = 0; i < 4; i++) {
    int m = bm + (ty << 2) + i;
#pragma unroll
    for (int j = 0; j < 4; j++) {
      int n = bn + (tx << 2) + j;
      float v = acc[i][j] + bias[n];
      float a = fmaxf(v, 0.0f);
      Aout[(size_t)m * N + n] = a;
      float asig = 2.0f / (1.0f + __expf(-a)) - 1.0f;
      float u = (asig - c0) * invw;
      U[(size_t)n * BDIM + m] = u;
    }
  }
}

// ---------------- GEMM2: x_hat = a @ w_dec + b_dec; fused recon-loss sum ----
__global__ __launch_bounds__(256) void gemm2_kernel(
    const float* __restrict__ A, const float* __restrict__ W,
    const float* __restrict__ bias, const float* __restrict__ X,
    float* __restrict__ out, float* __restrict__ accums)
{
  const int K = NDIM, N = PDIM;
  __shared__ float As[BK][BM + 4];
  __shared__ float Bs[BK][BN + 4];
  __shared__ float red[4];
  int tid = threadIdx.x;
  int bm = blockIdx.y * BM;
  int bn = blockIdx.x * BN;
  int ty = tid >> 4, tx = tid & 15;
  float acc[4][4] = {};
  for (int k0 = 0; k0 < K; k0 += BK) {
    int r = tid >> 2;
    int c = (tid & 3) << 2;
    float4 av = *(const float4*)(A + (size_t)(bm + r) * K + k0 + c);
    As[c + 0][r] = av.x; As[c + 1][r] = av.y; As[c + 2][r] = av.z; As[c + 3][r] = av.w;
    int rb = tid >> 4;
    int cb = (tid & 15) << 2;
    *(float4*)(&Bs[rb][cb]) = *(const float4*)(W + (size_t)(k0 + rb) * N + bn + cb);
    __syncthreads();
#pragma unroll
    for (int k = 0; k < BK; ++k) {
      float4 a4 = *(const float4*)(&As[k][ty << 2]);
      float4 b4 = *(const float4*)(&Bs[k][tx << 2]);
      float ar[4] = {a4.x, a4.y, a4.z, a4.w};
      float br[4] = {b4.x, b4.y, b4.z, b4.w};
#pragma unroll
      for (int i = 0; i < 4; i++)
#pragma unroll
        for (int j = 0; j < 4; j++)
          acc[i][j] = fmaf(ar[i], br[j], acc[i][j]);
    }
    __syncthreads();
  }
  float local = 0.0f;
#pragma unroll
  for (int i = 0; i < 4; i++) {
    int m = bm + (ty << 2) + i;
#pragma unroll
    for (int j = 0; j < 4; j++) {
      int n = bn + (tx << 2) + j;
      float xh = acc[i][j] + bias[n];
      out[(size_t)m * N + n] = xh;
      float d = xh - X[(size_t)m * N + n];
      local = fmaf(d, d, local);
    }
  }
#pragma unroll
  for (int d = 32; d >= 1; d >>= 1) local += __shfl_xor(local, d);
  if ((tid & 63) == 0) red[tid >> 6] = local;
  __syncthreads();
  if (tid == 0) atomicAdd(accums + 0, red[0] + red[1] + red[2] + red[3]);
}

// ---------------- MLE: 15 gradient-ascent steps per neuron + entropy ----
__global__ __launch_bounds__(64) void mle_kernel(
    const float* __restrict__ U, const float* __restrict__ thetas,
    float* __restrict__ ent_out, float* __restrict__ accums)
{
  int n = blockIdx.x;
  int lane = threadIdx.x;
  __shared__ float th_s[TDIM];
  __shared__ float pi_s[TDIM];
  __shared__ float s_s[64 * 33];

  // preload bucket index/frac (invariant across MLE steps)
  float f_reg[8];
  int j_reg[8];
#pragma unroll
  for (int i = 0; i < 8; i++) {
    float u = U[(size_t)n * BDIM + lane + i * 64];
    int j = (int)u;
    if (j > TDIM - 2) j = TDIM - 2;
    if (j < 0) j = 0;
    f_reg[i] = u - (float)j;
    j_reg[i] = j;
  }
  if (lane < TDIM) th_s[lane] = thetas[(size_t)n * TDIM + lane];
  __syncthreads();

  for (int step = 0; step < 15; ++step) {
    // softmax over 32 (upper 32 lanes mirror)
    float t = th_s[lane & 31];
    float mx = t;
#pragma unroll
    for (int d = 16; d >= 1; d >>= 1) mx = fmaxf(mx, __shfl_xor(mx, d));
    float e = __expf(t - mx);
    float se = e;
#pragma unroll
    for (int d = 16; d >= 1; d >>= 1) se += __shfl_xor(se, d);
    float pv = e / se;
    if (lane < TDIM) pi_s[lane] = pv;
    // zero private slice (stride 33 -> bank (lane+j)%32, conflict-free scatter)
#pragma unroll
    for (int i = 0; i < 33; i++) s_s[lane * 33 + i] = 0.0f;
    __syncthreads();

    float S_local = 0.0f;
#pragma unroll
    for (int i = 0; i < 8; i++) {
      int j = j_reg[i];
      float f = f_reg[i];
      float p = (1.0f - f) * pi_s[j] + f * pi_s[j + 1];
      float r = 1.0f / (p + EPSC);
      S_local = fmaf(p, r, S_local);
      float* sp = &s_s[lane * 33 + j];
      sp[0] += (1.0f - f) * r;
      sp[1] += f * r;
    }
    __syncthreads();
    float S = S_local;
#pragma unroll
    for (int d = 32; d >= 1; d >>= 1) S += __shfl_xor(S, d);
    if (lane < TDIM) {
      float acc = 0.0f;
#pragma unroll 8
      for (int L = 0; L < 64; ++L) acc += s_s[L * 33 + lane];
      th_s[lane] += 0.01f * pv * (acc - S);
    }
    __syncthreads();
  }

  // final softmax + entropy
  float t = th_s[lane & 31];
  float mx = t;
#pragma unroll
  for (int d = 16; d >= 1; d >>= 1) mx = fmaxf(mx, __shfl_xor(mx, d));
  float e = __expf(t - mx);
  float se = e;
#pragma unroll
  for (int d = 16; d >= 1; d >>= 1) se += __shfl_xor(se, d);
  if (lane < TDIM) pi_s[lane] = e / se;
  __syncthreads();
  float ent_local = 0.0f;
#pragma unroll
  for (int i = 0; i < 8; i++) {
    int j = j_reg[i];
    float f = f_reg[i];
    float p = (1.0f - f) * pi_s[j] + f * pi_s[j + 1];
    ent_local = fmaf(p, __logf(p + EPSC), ent_local);
  }
  float E = ent_local;
#pragma unroll
  for (int d = 32; d >= 1; d >>= 1) E += __shfl_xor(E, d);
  if (lane == 0) {
    float entn = -E;
    ent_out[n] = entn;
    atomicAdd(accums + 1, entn);
  }
}

// ---------------- decay: sum(w_enc^2) + sum(w_dec^2) ----
__global__ __launch_bounds__(256) void decay_kernel(
    const float* __restrict__ w1, const float* __restrict__ w2,
    float* __restrict__ accums)
{
  __shared__ float red[4];
  int idx = blockIdx.x * blockDim.x + threadIdx.x;
  int stride = gridDim.x * blockDim.x;
  const int n4 = (PDIM * NDIM) / 4;
  float local = 0.0f;
  const float4* a4 = (const float4*)w1;
  const float4* b4 = (const float4*)w2;
  for (int i = idx; i < n4; i += stride) {
    float4 a = a4[i];
    local = fmaf(a.x, a.x, local);
    local = fmaf(a.y, a.y, local);
    local = fmaf(a.z, a.z, local);
    local = fmaf(a.w, a.w, local);
    float4 b = b4[i];
    local = fmaf(b.x, b.x, local);
    local = fmaf(b.y, b.y, local);
    local = fmaf(b.z, b.z, local);
    local = fmaf(b.w, b.w, local);
  }
#pragma unroll
  for (int d = 32; d >= 1; d >>= 1) local += __shfl_xor(local, d);
  if ((threadIdx.x & 63) == 0) red[threadIdx.x >> 6] = local;
  __syncthreads();
  if (threadIdx.x == 0) atomicAdd(accums + 2, red[0] + red[1] + red[2] + red[3]);
}

__global__ void init_kernel(float* accums) {
  if (threadIdx.x < 4) accums[threadIdx.x] = 0.0f;
}

__global__ void finalize_kernel(const float* __restrict__ accums, float* __restrict__ out) {
  if (threadIdx.x == 0) {
    float recon = accums[0] * (0.5f / (float)BDIM);
    float entl = 0.01f * accums[1];
    float decay = 0.00025f * accums[2];
    out[(size_t)BDIM * PDIM + NDIM] = recon + entl + decay;
  }
}

extern "C" void kernel_launch(void* const* d_in, const int* in_sizes, int n_in,
                              void* d_out, int out_size, void* d_ws, size_t ws_size,
                              hipStream_t stream) {
  (void)in_sizes; (void)n_in; (void)out_size; (void)ws_size;
  const float* x       = (const float*)d_in[0];
  const float* w_enc   = (const float*)d_in[1];
  const float* b_enc   = (const float*)d_in[2];
  const float* w_dec   = (const float*)d_in[3];
  const float* b_dec   = (const float*)d_in[4];
  const float* thetas  = (const float*)d_in[5];
  const float* centers = (const float*)d_in[6];
  float* out = (float*)d_out;

  float* Aout   = (float*)d_ws;                                        // B*N floats
  float* accums = (float*)((char*)d_ws + (size_t)BDIM * NDIM * 4);     // 4 floats
  float* U      = out;                                                 // reuse x_hat region as scratch (N*B == B*P)
  float* ent_out = out + (size_t)BDIM * PDIM;

  hipLaunchKernelGGL(init_kernel, dim3(1), dim3(64), 0, stream, accums);
  hipLaunchKernelGGL(gemm1_kernel, dim3(NDIM / BN, BDIM / BM), dim3(256), 0, stream,
                     x, w_enc, b_enc, centers, Aout, U);
  hipLaunchKernelGGL(mle_kernel, dim3(NDIM), dim3(64), 0, stream, U, thetas, ent_out, accums);
  hipLaunchKernelGGL(decay_kernel, dim3(256), dim3(256), 0, stream, w_enc, w_dec, accums);
  hipLaunchKernelGGL(gemm2_kernel, dim3(PDIM / BN, BDIM / BM), dim3(256), 0, stream,
                     Aout, w_dec, b_dec, x, out, accums);
  hipLaunchKernelGGL(finalize_kernel, dim3(1), dim3(64), 0, stream, accums, out);
}

// Round 2
// 175.827 us; speedup vs baseline: 1.3405x; 1.3405x over previous
//
#include <hip/hip_runtime.h>

#define EPSC 1e-10f
#define BDIM 512
#define PDIM 1024
#define NDIM 1024
#define TDIM 32

// ---- split-K GEMM: P[z] = A[512xK-half z] @ B[1024x1024]; optional w^2 sum fused ----
// tile 64x64, BK=16, 256 threads, 4x4 per thread, double-buffered LDS + register prefetch
__global__ __launch_bounds__(256) void gemm_splitk_kernel(
    const float* __restrict__ A, const float* __restrict__ B,
    float* __restrict__ P, float* __restrict__ accums, int zero_accums)
{
  const int K = 1024, N = 1024;
  __shared__ float As[2][16][68];
  __shared__ float Bs[2][16][68];
  __shared__ float red[4];
  int tid = threadIdx.x;
  if (zero_accums && blockIdx.x == 0 && blockIdx.y == 0 && blockIdx.z == 0 && tid < 4)
    accums[tid] = 0.0f;
  int bm = blockIdx.y * 64;
  int bn = blockIdx.x * 64;
  int kbase = blockIdx.z * 512;
  int ty = tid >> 4, tx = tid & 15;
  int ar = tid >> 2, ac = (tid & 3) << 2;   // A staging: row ar (0..63), k-col ac
  int br = tid >> 4, bc = (tid & 15) << 2;  // B staging: k-row br (0..15), col bc
  const float* Aptr = A + (size_t)(bm + ar) * K + kbase + ac;
  const float* Bptr = B + (size_t)(kbase + br) * N + bn + bc;

  bool do_wsq = (blockIdx.y == 0);   // fused sum(w^2): each (k,n) of B loaded exactly once by y==0 blocks
  float wsq = 0.0f;

  float4 av = *(const float4*)Aptr;
  float4 bv = *(const float4*)Bptr;
  if (do_wsq) { wsq = fmaf(bv.x, bv.x, wsq); wsq = fmaf(bv.y, bv.y, wsq); wsq = fmaf(bv.z, bv.z, wsq); wsq = fmaf(bv.w, bv.w, wsq); }
  As[0][ac + 0][ar] = av.x; As[0][ac + 1][ar] = av.y; As[0][ac + 2][ar] = av.z; As[0][ac + 3][ar] = av.w;
  *(float4*)&Bs[0][br][bc] = bv;
  __syncthreads();

  float acc[4][4] = {};
#pragma unroll 2
  for (int it = 0; it < 32; ++it) {
    int cur = it & 1;
    if (it < 31) {
      av = *(const float4*)(Aptr + (it + 1) * 16);
      bv = *(const float4*)(Bptr + (size_t)(it + 1) * 16 * N);
    }
#pragma unroll
    for (int k = 0; k < 16; ++k) {
      float4 a4 = *(const float4*)&As[cur][k][ty << 2];
      float4 b4 = *(const float4*)&Bs[cur][k][tx << 2];
      float arr[4] = {a4.x, a4.y, a4.z, a4.w};
      float brr[4] = {b4.x, b4.y, b4.z, b4.w};
#pragma unroll
      for (int i = 0; i < 4; i++)
#pragma unroll
        for (int j = 0; j < 4; j++)
          acc[i][j] = fmaf(arr[i], brr[j], acc[i][j]);
    }
    if (it < 31) {
      int nxt = cur ^ 1;
      if (do_wsq) { wsq = fmaf(bv.x, bv.x, wsq); wsq = fmaf(bv.y, bv.y, wsq); wsq = fmaf(bv.z, bv.z, wsq); wsq = fmaf(bv.w, bv.w, wsq); }
      As[nxt][ac + 0][ar] = av.x; As[nxt][ac + 1][ar] = av.y; As[nxt][ac + 2][ar] = av.z; As[nxt][ac + 3][ar] = av.w;
      *(float4*)&Bs[nxt][br][bc] = bv;
    }
    __syncthreads();
  }

  float* Po = P + (size_t)blockIdx.z * BDIM * NDIM;
#pragma unroll
  for (int i = 0; i < 4; i++) {
    *(float4*)(Po + (size_t)(bm + (ty << 2) + i) * N + bn + (tx << 2)) =
        make_float4(acc[i][0], acc[i][1], acc[i][2], acc[i][3]);
  }

  if (do_wsq) {
#pragma unroll
    for (int d = 32; d >= 1; d >>= 1) wsq += __shfl_xor(wsq, d);
    if ((tid & 63) == 0) red[tid >> 6] = wsq;
    __syncthreads();
    if (tid == 0) atomicAdd(accums + 2, red[0] + red[1] + red[2] + red[3]);
  }
}

// ---- epilogue 1: a = relu(P0+P1+b); Aout[b][n]=a; U[n][b]=(sig(a)-c0)/w via LDS transpose ----
__global__ __launch_bounds__(256) void ep1_kernel(
    const float* __restrict__ P, const float* __restrict__ bias,
    const float* __restrict__ centers,
    float* __restrict__ Aout, float* __restrict__ U)
{
  __shared__ float T[64][69];   // T[b][n] within tile; stride 69 -> worst 2-way (free)
  int tid = threadIdx.x;
  int bn = blockIdx.x * 64;
  int bm = blockIdx.y * 64;
  int ty = tid >> 4;   // 0..15
  int tx = tid & 15;
  float c0 = centers[0];
  float invw = 1.0f / (centers[1] - centers[0]);
  const float* P1 = P + (size_t)BDIM * NDIM;
#pragma unroll
  for (int i = 0; i < 4; ++i) {
    int row = ty + i * 16;       // b within tile
    int col = tx << 2;           // n within tile
    size_t off = (size_t)(bm + row) * NDIM + bn + col;
    float4 p0 = *(const float4*)(P + off);
    float4 p1 = *(const float4*)(P1 + off);
    float4 bsv = *(const float4*)(bias + bn + col);
    float a0 = fmaxf(p0.x + p1.x + bsv.x, 0.0f);
    float a1 = fmaxf(p0.y + p1.y + bsv.y, 0.0f);
    float a2 = fmaxf(p0.z + p1.z + bsv.z, 0.0f);
    float a3 = fmaxf(p0.w + p1.w + bsv.w, 0.0f);
    *(float4*)(Aout + off) = make_float4(a0, a1, a2, a3);
    T[row][col + 0] = (2.0f / (1.0f + __expf(-a0)) - 1.0f - c0) * invw;
    T[row][col + 1] = (2.0f / (1.0f + __expf(-a1)) - 1.0f - c0) * invw;
    T[row][col + 2] = (2.0f / (1.0f + __expf(-a2)) - 1.0f - c0) * invw;
    T[row][col + 3] = (2.0f / (1.0f + __expf(-a3)) - 1.0f - c0) * invw;
  }
  __syncthreads();
#pragma unroll
  for (int i = 0; i < 4; ++i) {
    int rr = ty + i * 16;        // n within tile
    int cc = tx << 2;            // b within tile
    float4 uv = make_float4(T[cc + 0][rr], T[cc + 1][rr], T[cc + 2][rr], T[cc + 3][rr]);
    *(float4*)(U + (size_t)(bn + rr) * BDIM + bm + cc) = uv;
  }
}

// ---- MLE: 15 gradient-ascent steps per neuron + entropy ----
__global__ __launch_bounds__(64) void mle_kernel(
    const float* __restrict__ U, const float* __restrict__ thetas,
    float* __restrict__ ent_out, float* __restrict__ accums)
{
  int n = blockIdx.x;
  int lane = threadIdx.x;
  __shared__ float th_s[TDIM];
  __shared__ float pi_s[TDIM];
  __shared__ float s_s[64 * 33];

  float f_reg[8];
  int j_reg[8];
#pragma unroll
  for (int i = 0; i < 8; i++) {
    float u = U[(size_t)n * BDIM + lane + i * 64];
    int j = (int)u;
    if (j > TDIM - 2) j = TDIM - 2;
    f_reg[i] = u - (float)j;
    j_reg[i] = j;
  }
  if (lane < TDIM) th_s[lane] = thetas[(size_t)n * TDIM + lane];
  __syncthreads();

  int h = lane >> 5, t = lane & 31;
  for (int step = 0; step < 15; ++step) {
    float tv = th_s[lane & 31];
    float mx = tv;
#pragma unroll
    for (int d = 16; d >= 1; d >>= 1) mx = fmaxf(mx, __shfl_xor(mx, d));
    float e = __expf(tv - mx);
    float se = e;
#pragma unroll
    for (int d = 16; d >= 1; d >>= 1) se += __shfl_xor(se, d);
    float pv = e / se;
    if (lane < TDIM) pi_s[lane] = pv;
#pragma unroll
    for (int i = 0; i < 33; i++) s_s[lane * 33 + i] = 0.0f;
    __syncthreads();

    float S_local = 0.0f;
#pragma unroll
    for (int i = 0; i < 8; i++) {
      int j = j_reg[i];
      float f = f_reg[i];
      float p = (1.0f - f) * pi_s[j] + f * pi_s[j + 1];
      float r = 1.0f / (p + EPSC);
      S_local = fmaf(p, r, S_local);
      float* sp = &s_s[lane * 33 + j];
      sp[0] += (1.0f - f) * r;
      sp[1] += f * r;
    }
    __syncthreads();
    float S = S_local;
#pragma unroll
    for (int d = 32; d >= 1; d >>= 1) S += __shfl_xor(S, d);
    float colsum = 0.0f;
#pragma unroll 8
    for (int L = 0; L < 32; ++L) colsum += s_s[(h * 32 + L) * 33 + t];
    colsum += __shfl_xor(colsum, 32);
    if (lane < TDIM) th_s[lane] += 0.01f * pv * (colsum - S);
    __syncthreads();
  }

  float tv = th_s[lane & 31];
  float mx = tv;
#pragma unroll
  for (int d = 16; d >= 1; d >>= 1) mx = fmaxf(mx, __shfl_xor(mx, d));
  float e = __expf(tv - mx);
  float se = e;
#pragma unroll
  for (int d = 16; d >= 1; d >>= 1) se += __shfl_xor(se, d);
  if (lane < TDIM) pi_s[lane] = e / se;
  __syncthreads();
  float ent_local = 0.0f;
#pragma unroll
  for (int i = 0; i < 8; i++) {
    int j = j_reg[i];
    float f = f_reg[i];
    float p = (1.0f - f) * pi_s[j] + f * pi_s[j + 1];
    ent_local = fmaf(p, __logf(p + EPSC), ent_local);
  }
  float E = ent_local;
#pragma unroll
  for (int d = 32; d >= 1; d >>= 1) E += __shfl_xor(E, d);
  if (lane == 0) {
    float entn = -E;
    ent_out[n] = entn;
    atomicAdd(accums + 1, entn);
  }
}

// ---- epilogue 2: x_hat = P0+P1+b_dec; recon-loss sum ----
__global__ __launch_bounds__(256) void ep2_kernel(
    const float* __restrict__ P, const float* __restrict__ bias,
    const float* __restrict__ X, float* __restrict__ out, float* __restrict__ accums)
{
  __shared__ float red[4];
  int gid = blockIdx.x * 256 + threadIdx.x;   // 0..131071 (B*P/4)
  const float* P1 = P + (size_t)BDIM * PDIM;
  size_t off = (size_t)gid << 2;
  float4 p0 = *(const float4*)(P + off);
  float4 p1 = *(const float4*)(P1 + off);
  float4 bv = *(const float4*)(bias + ((gid & 255) << 2));
  float4 xv = *(const float4*)(X + off);
  float xh0 = p0.x + p1.x + bv.x;
  float xh1 = p0.y + p1.y + bv.y;
  float xh2 = p0.z + p1.z + bv.z;
  float xh3 = p0.w + p1.w + bv.w;
  *(float4*)(out + off) = make_float4(xh0, xh1, xh2, xh3);
  float d0 = xh0 - xv.x, d1 = xh1 - xv.y, d2 = xh2 - xv.z, d3 = xh3 - xv.w;
  float local = d0 * d0 + d1 * d1 + d2 * d2 + d3 * d3;
#pragma unroll
  for (int d = 32; d >= 1; d >>= 1) local += __shfl_xor(local, d);
  if ((threadIdx.x & 63) == 0) red[threadIdx.x >> 6] = local;
  __syncthreads();
  if (threadIdx.x == 0) atomicAdd(accums + 0, red[0] + red[1] + red[2] + red[3]);
}

__global__ void finalize_kernel(const float* __restrict__ accums, float* __restrict__ out) {
  if (threadIdx.x == 0) {
    float recon = accums[0] * (0.5f / (float)BDIM);
    float entl = 0.01f * accums[1];
    float decay = 0.00025f * accums[2];
    out[(size_t)BDIM * PDIM + NDIM] = recon + entl + decay;
  }
}

extern "C" void kernel_launch(void* const* d_in, const int* in_sizes, int n_in,
                              void* d_out, int out_size, void* d_ws, size_t ws_size,
                              hipStream_t stream) {
  (void)in_sizes; (void)n_in; (void)out_size; (void)ws_size;
  const float* x       = (const float*)d_in[0];
  const float* w_enc   = (const float*)d_in[1];
  const float* b_enc   = (const float*)d_in[2];
  const float* w_dec   = (const float*)d_in[3];
  const float* b_dec   = (const float*)d_in[4];
  const float* thetas  = (const float*)d_in[5];
  const float* centers = (const float*)d_in[6];
  float* out = (float*)d_out;

  float* Pbuf   = (float*)d_ws;                                          // 2 * B*N floats (4 MB)
  float* Aout   = (float*)((char*)d_ws + 2 * (size_t)BDIM * NDIM * 4);   // B*N floats (2 MB)
  float* accums = (float*)((char*)d_ws + 3 * (size_t)BDIM * NDIM * 4);   // 4 floats
  float* U      = out;                                                   // reuse x_hat region (freed before ep2)
  float* ent_out = out + (size_t)BDIM * PDIM;

  hipLaunchKernelGGL(gemm_splitk_kernel, dim3(16, 8, 2), dim3(256), 0, stream,
                     x, w_enc, Pbuf, accums, 1);
  hipLaunchKernelGGL(ep1_kernel, dim3(16, 8), dim3(256), 0, stream,
                     Pbuf, b_enc, centers, Aout, U);
  hipLaunchKernelGGL(mle_kernel, dim3(NDIM), dim3(64), 0, stream, U, thetas, ent_out, accums);
  hipLaunchKernelGGL(gemm_splitk_kernel, dim3(16, 8, 2), dim3(256), 0, stream,
                     Aout, w_dec, Pbuf, accums, 0);
  hipLaunchKernelGGL(ep2_kernel, dim3(512), dim3(256), 0, stream,
                     Pbuf, b_dec, x, out, accums);
  hipLaunchKernelGGL(finalize_kernel, dim3(1), dim3(64), 0, stream, accums, out);
}

// Round 3
// 152.372 us; speedup vs baseline: 1.5468x; 1.1539x over previous
//
#include <hip/hip_runtime.h>

#define EPSC 1e-10f
#define BDIM 512
#define PDIM 1024
#define NDIM 1024
#define TDIM 32

typedef __attribute__((ext_vector_type(8))) short short8;
typedef __attribute__((ext_vector_type(4))) float f32x4;

static __device__ __forceinline__ short f2bf(float f) {
  unsigned u = __float_as_uint(f);
  unsigned r = (u + 0x7fffu + ((u >> 16) & 1u)) >> 16;
  return (short)r;
}

// ---- conv_x: x fp32 -> bf16 (same layout); block 0 zeroes accums ----
__global__ __launch_bounds__(256) void conv_x_kernel(
    const float* __restrict__ X, short* __restrict__ Xbf, float* __restrict__ accums)
{
  int tid = threadIdx.x;
  if (blockIdx.x == 0 && tid < 4) accums[tid] = 0.0f;
  size_t base = (size_t)blockIdx.x * 2048 + (size_t)tid * 8;
  float4 v0 = *(const float4*)(X + base);
  float4 v1 = *(const float4*)(X + base + 4);
  short8 o;
  o[0] = f2bf(v0.x); o[1] = f2bf(v0.y); o[2] = f2bf(v0.z); o[3] = f2bf(v0.w);
  o[4] = f2bf(v1.x); o[5] = f2bf(v1.y); o[6] = f2bf(v1.z); o[7] = f2bf(v1.w);
  *(short8*)(Xbf + base) = o;
}

// ---- conv_w: fp32 [k][n] -> bf16 transposed [n][k]; fused sum(w^2) ----
__global__ __launch_bounds__(256) void conv_w_kernel(
    const float* __restrict__ W1, const float* __restrict__ W2,
    short* __restrict__ T1, short* __restrict__ T2, float* __restrict__ accums)
{
  __shared__ float T[64][65];
  __shared__ float red[4];
  const float* src = blockIdx.z ? W2 : W1;
  short* dst = blockIdx.z ? T2 : T1;
  int tid = threadIdx.x;
  int r0 = blockIdx.y * 64;   // k rows
  int c0 = blockIdx.x * 64;   // n cols
  float wsq = 0.0f;
#pragma unroll
  for (int i = 0; i < 4; ++i) {
    int row = (tid >> 4) + i * 16;
    int col = (tid & 15) << 2;
    float4 v = *(const float4*)(src + (size_t)(r0 + row) * NDIM + c0 + col);
    T[row][col + 0] = v.x; T[row][col + 1] = v.y; T[row][col + 2] = v.z; T[row][col + 3] = v.w;
    wsq = fmaf(v.x, v.x, wsq); wsq = fmaf(v.y, v.y, wsq);
    wsq = fmaf(v.z, v.z, wsq); wsq = fmaf(v.w, v.w, wsq);
  }
  __syncthreads();
  int n = tid >> 2;              // 0..63
  int kb = (tid & 3) << 4;       // 0,16,32,48
  short8 o0, o1;
#pragma unroll
  for (int i = 0; i < 8; ++i) o0[i] = f2bf(T[kb + i][n]);
#pragma unroll
  for (int i = 0; i < 8; ++i) o1[i] = f2bf(T[kb + 8 + i][n]);
  short* dp = dst + (size_t)(c0 + n) * NDIM + r0 + kb;
  *(short8*)dp = o0;
  *(short8*)(dp + 8) = o1;
#pragma unroll
  for (int d = 32; d >= 1; d >>= 1) wsq += __shfl_xor(wsq, d);
  if ((tid & 63) == 0) red[tid >> 6] = wsq;
  __syncthreads();
  if (tid == 0) atomicAdd(accums + 2, red[0] + red[1] + red[2] + red[3]);
}

// ---- gemm1: a = relu(x@w_enc + b); Abf (bf16), U[n][b] = (sig(a)-c0)/width ----
// block: 4 waves, tile 64(M)x32(N); wave: 16x32 via 2x mfma_16x16x32; no LDS
__global__ __launch_bounds__(256) void gemm1_mfma(
    const short* __restrict__ Xbf, const short* __restrict__ WT,
    const float* __restrict__ bias, const float* __restrict__ centers,
    short* __restrict__ Abf, float* __restrict__ U)
{
  int tid = threadIdx.x;
  int lane = tid & 63, wid = tid >> 6;
  int q = lane >> 4, r16 = lane & 15;
  int bn = blockIdx.x * 32;
  int m = blockIdx.y * 64 + wid * 16 + r16;
  const short* ap  = Xbf + (size_t)m * NDIM + q * 8;
  const short* b0p = WT + (size_t)(bn + r16) * NDIM + q * 8;
  const short* b1p = b0p + 16 * NDIM;
  f32x4 acc0 = {0.f, 0.f, 0.f, 0.f};
  f32x4 acc1 = {0.f, 0.f, 0.f, 0.f};
#pragma unroll 4
  for (int k = 0; k < NDIM; k += 32) {
    short8 a  = *(const short8*)(ap + k);
    short8 b0 = *(const short8*)(b0p + k);
    short8 b1 = *(const short8*)(b1p + k);
    acc0 = __builtin_amdgcn_mfma_f32_16x16x32_bf16(a, b0, acc0, 0, 0, 0);
    acc1 = __builtin_amdgcn_mfma_f32_16x16x32_bf16(a, b1, acc1, 0, 0, 0);
  }
  float c0 = centers[0];
  float invw = 1.0f / (centers[1] - centers[0]);
  int mrow = blockIdx.y * 64 + wid * 16 + (q << 2);
  int n0 = bn + r16;
  float bi0 = bias[n0], bi1 = bias[n0 + 16];
#pragma unroll
  for (int r = 0; r < 4; ++r) {
    int mm = mrow + r;
    float a0 = fmaxf(acc0[r] + bi0, 0.0f);
    float a1 = fmaxf(acc1[r] + bi1, 0.0f);
    Abf[(size_t)mm * NDIM + n0]      = f2bf(a0);
    Abf[(size_t)mm * NDIM + n0 + 16] = f2bf(a1);
    U[(size_t)n0 * BDIM + mm]        = (2.0f / (1.0f + __expf(-a0)) - 1.0f - c0) * invw;
    U[(size_t)(n0 + 16) * BDIM + mm] = (2.0f / (1.0f + __expf(-a1)) - 1.0f - c0) * invw;
  }
}

// ---- gemm2: x_hat = a@w_dec + b_dec; fused recon-loss ----
__global__ __launch_bounds__(256) void gemm2_mfma(
    const short* __restrict__ Abf, const short* __restrict__ WdT,
    const float* __restrict__ bias, const float* __restrict__ X,
    float* __restrict__ out, float* __restrict__ accums)
{
  __shared__ float red[4];
  int tid = threadIdx.x;
  int lane = tid & 63, wid = tid >> 6;
  int q = lane >> 4, r16 = lane & 15;
  int bn = blockIdx.x * 32;
  int m = blockIdx.y * 64 + wid * 16 + r16;
  const short* ap  = Abf + (size_t)m * NDIM + q * 8;
  const short* b0p = WdT + (size_t)(bn + r16) * NDIM + q * 8;
  const short* b1p = b0p + 16 * NDIM;
  f32x4 acc0 = {0.f, 0.f, 0.f, 0.f};
  f32x4 acc1 = {0.f, 0.f, 0.f, 0.f};
#pragma unroll 4
  for (int k = 0; k < NDIM; k += 32) {
    short8 a  = *(const short8*)(ap + k);
    short8 b0 = *(const short8*)(b0p + k);
    short8 b1 = *(const short8*)(b1p + k);
    acc0 = __builtin_amdgcn_mfma_f32_16x16x32_bf16(a, b0, acc0, 0, 0, 0);
    acc1 = __builtin_amdgcn_mfma_f32_16x16x32_bf16(a, b1, acc1, 0, 0, 0);
  }
  int mrow = blockIdx.y * 64 + wid * 16 + (q << 2);
  int p0 = bn + r16;
  float bi0 = bias[p0], bi1 = bias[p0 + 16];
  float local = 0.0f;
#pragma unroll
  for (int r = 0; r < 4; ++r) {
    int mm = mrow + r;
    float xh0 = acc0[r] + bi0;
    float xh1 = acc1[r] + bi1;
    out[(size_t)mm * PDIM + p0]      = xh0;
    out[(size_t)mm * PDIM + p0 + 16] = xh1;
    float d0 = xh0 - X[(size_t)mm * PDIM + p0];
    float d1 = xh1 - X[(size_t)mm * PDIM + p0 + 16];
    local = fmaf(d0, d0, local);
    local = fmaf(d1, d1, local);
  }
#pragma unroll
  for (int d = 32; d >= 1; d >>= 1) local += __shfl_xor(local, d);
  if ((tid & 63) == 0) red[tid >> 6] = local;
  __syncthreads();
  if (tid == 0) atomicAdd(accums + 0, red[0] + red[1] + red[2] + red[3]);
}

// ---- MLE: 15 gradient-ascent steps per neuron + entropy ----
__global__ __launch_bounds__(64) void mle_kernel(
    const float* __restrict__ U, const float* __restrict__ thetas,
    float* __restrict__ ent_out, float* __restrict__ accums)
{
  int n = blockIdx.x;
  int lane = threadIdx.x;
  __shared__ float th_s[TDIM];
  __shared__ float pi_s[TDIM];
  __shared__ float s_s[64 * 33];

  float f_reg[8];
  int j_reg[8];
#pragma unroll
  for (int i = 0; i < 8; i++) {
    float u = U[(size_t)n * BDIM + lane + i * 64];
    int j = (int)u;
    if (j > TDIM - 2) j = TDIM - 2;
    f_reg[i] = u - (float)j;
    j_reg[i] = j;
  }
  if (lane < TDIM) th_s[lane] = thetas[(size_t)n * TDIM + lane];
  __syncthreads();

  int h = lane >> 5, t = lane & 31;
  for (int step = 0; step < 15; ++step) {
    float tv = th_s[lane & 31];
    float mx = tv;
#pragma unroll
    for (int d = 16; d >= 1; d >>= 1) mx = fmaxf(mx, __shfl_xor(mx, d));
    float e = __expf(tv - mx);
    float se = e;
#pragma unroll
    for (int d = 16; d >= 1; d >>= 1) se += __shfl_xor(se, d);
    float pv = e / se;
    if (lane < TDIM) pi_s[lane] = pv;
#pragma unroll
    for (int i = 0; i < 33; i++) s_s[lane * 33 + i] = 0.0f;
    __syncthreads();

    float S_local = 0.0f;
#pragma unroll
    for (int i = 0; i < 8; i++) {
      int j = j_reg[i];
      float f = f_reg[i];
      float p = (1.0f - f) * pi_s[j] + f * pi_s[j + 1];
      float r = 1.0f / (p + EPSC);
      S_local = fmaf(p, r, S_local);
      float* sp = &s_s[lane * 33 + j];
      sp[0] += (1.0f - f) * r;
      sp[1] += f * r;
    }
    __syncthreads();
    float S = S_local;
#pragma unroll
    for (int d = 32; d >= 1; d >>= 1) S += __shfl_xor(S, d);
    float colsum = 0.0f;
#pragma unroll 8
    for (int L = 0; L < 32; ++L) colsum += s_s[(h * 32 + L) * 33 + t];
    colsum += __shfl_xor(colsum, 32);
    if (lane < TDIM) th_s[lane] += 0.01f * pv * (colsum - S);
    __syncthreads();
  }

  float tv = th_s[lane & 31];
  float mx = tv;
#pragma unroll
  for (int d = 16; d >= 1; d >>= 1) mx = fmaxf(mx, __shfl_xor(mx, d));
  float e = __expf(tv - mx);
  float se = e;
#pragma unroll
  for (int d = 16; d >= 1; d >>= 1) se += __shfl_xor(se, d);
  if (lane < TDIM) pi_s[lane] = e / se;
  __syncthreads();
  float ent_local = 0.0f;
#pragma unroll
  for (int i = 0; i < 8; i++) {
    int j = j_reg[i];
    float f = f_reg[i];
    float p = (1.0f - f) * pi_s[j] + f * pi_s[j + 1];
    ent_local = fmaf(p, __logf(p + EPSC), ent_local);
  }
  float E = ent_local;
#pragma unroll
  for (int d = 32; d >= 1; d >>= 1) E += __shfl_xor(E, d);
  if (lane == 0) {
    float entn = -E;
    ent_out[n] = entn;
    atomicAdd(accums + 1, entn);
  }
}

__global__ void finalize_kernel(const float* __restrict__ accums, float* __restrict__ out) {
  if (threadIdx.x == 0) {
    float recon = accums[0] * (0.5f / (float)BDIM);
    float entl = 0.01f * accums[1];
    float decay = 0.00025f * accums[2];
    out[(size_t)BDIM * PDIM + NDIM] = recon + entl + decay;
  }
}

extern "C" void kernel_launch(void* const* d_in, const int* in_sizes, int n_in,
                              void* d_out, int out_size, void* d_ws, size_t ws_size,
                              hipStream_t stream) {
  (void)in_sizes; (void)n_in; (void)out_size; (void)ws_size;
  const float* x       = (const float*)d_in[0];
  const float* w_enc   = (const float*)d_in[1];
  const float* b_enc   = (const float*)d_in[2];
  const float* w_dec   = (const float*)d_in[3];
  const float* b_dec   = (const float*)d_in[4];
  const float* thetas  = (const float*)d_in[5];
  const float* centers = (const float*)d_in[6];
  float* out = (float*)d_out;

  char* ws = (char*)d_ws;
  short* Xbf    = (short*)(ws);                       // 1 MB
  short* WT     = (short*)(ws + (1 << 20));           // 2 MB (w_enc^T bf16, [n][k])
  short* WdT    = (short*)(ws + (3 << 20));           // 2 MB (w_dec^T bf16, [p][n])
  short* Abf    = (short*)(ws + (5 << 20));           // 1 MB
  float* accums = (float*)(ws + (6 << 20));           // 16 B
  float* U      = out;                                // scratch until gemm2 overwrites
  float* ent_out = out + (size_t)BDIM * PDIM;

  hipLaunchKernelGGL(conv_x_kernel, dim3(256), dim3(256), 0, stream, x, Xbf, accums);
  hipLaunchKernelGGL(conv_w_kernel, dim3(16, 16, 2), dim3(256), 0, stream,
                     w_enc, w_dec, WT, WdT, accums);
  hipLaunchKernelGGL(gemm1_mfma, dim3(32, 8), dim3(256), 0, stream,
                     Xbf, WT, b_enc, centers, Abf, U);
  hipLaunchKernelGGL(mle_kernel, dim3(NDIM), dim3(64), 0, stream, U, thetas, ent_out, accums);
  hipLaunchKernelGGL(gemm2_mfma, dim3(32, 8), dim3(256), 0, stream,
                     Abf, WdT, b_dec, x, out, accums);
  hipLaunchKernelGGL(finalize_kernel, dim3(1), dim3(64), 0, stream, accums, out);
}